// Round 4
// baseline (1670.594 us; speedup 1.0000x reference)
//
#include <hip/hip_runtime.h>
#include <hip/hip_bf16.h>
#include <math.h>

constexpr int NN = 1024;          // nodes
constexpr int NB = 32;            // batch
constexpr int ROWS = NB * NN;     // 32768 rows for BN
constexpr int NSLICE = 8;         // colsum partial slices (deterministic)

using f32x4 = __attribute__((ext_vector_type(4))) float;
using s16x8 = __attribute__((ext_vector_type(8))) short;   // 8 bf16 (4 VGPRs)

__device__ inline unsigned short f2bf(float f) {
  unsigned u = __float_as_uint(f);
  unsigned r = (u + 0x7FFFu + ((u >> 16) & 1u)) >> 16;  // RTNE
  return (unsigned short)r;
}
__device__ inline float bf2f(unsigned short h) {
  return __uint_as_float((unsigned)h << 16);
}

// ---------------------------------------------------------------------------
// Laplacian: computed IN PLACE over A (harness restores inputs every launch).
// ---------------------------------------------------------------------------

__global__ __launch_bounds__(256) void colsum_w(float* __restrict__ A,
                                                const float* __restrict__ x,
                                                float* __restrict__ S) {
  const int b = blockIdx.z;
  const int j = blockIdx.x * 256 + threadIdx.x;
  const int slice = blockIdx.y;
  const int ibase = slice * 128;
  __shared__ float xs[128 * 3];
  for (int idx = threadIdx.x; idx < 384; idx += 256)
    xs[idx] = x[(size_t)(b * NN + ibase) * 3 + idx];
  const float xj0 = x[(size_t)(b * NN + j) * 3 + 0];
  const float xj1 = x[(size_t)(b * NN + j) * 3 + 1];
  const float xj2 = x[(size_t)(b * NN + j) * 3 + 2];
  __syncthreads();
  float s = 0.f;
  size_t off = ((size_t)b << 20) + (size_t)ibase * NN + j;
  for (int ii = 0; ii < 128; ++ii, off += NN) {
    float a = A[off];
    float dx = xj0 - xs[ii * 3 + 0];
    float dy = xj1 - xs[ii * 3 + 1];
    float dz = xj2 - xs[ii * 3 + 2];
    float dist = sqrtf(dx * dx + dy * dy + dz * dz);
    float w = a / (dist + 0.001f);
    A[off] = w;
    s += w;
  }
  S[(size_t)slice * ROWS + b * NN + j] = s;
}

__global__ __launch_bounds__(256) void d_kernel(const float* __restrict__ S,
                                                float* __restrict__ D) {
  int i = blockIdx.x * 256 + threadIdx.x;
  if (i < ROWS) {
    float s = 0.f;
#pragma unroll
    for (int p = 0; p < NSLICE; ++p) s += S[(size_t)p * ROWS + i];
    D[i] = 1.f / sqrtf(s);
  }
}

__global__ __launch_bounds__(256) void scale_L(float* __restrict__ A,
                                               const float* __restrict__ D) {
  const long total4 = (long)NB * NN * NN / 4;
  for (long idx = (long)blockIdx.x * 256 + threadIdx.x; idx < total4;
       idx += (long)gridDim.x * 256) {
    long base = idx * 4;
    int j0 = (int)(base & (NN - 1));
    int i = (int)((base >> 10) & (NN - 1));
    int b = (int)(base >> 20);
    float4 w = reinterpret_cast<float4*>(A)[idx];
    float di = D[b * NN + i];
    float4 dj = *reinterpret_cast<const float4*>(&D[b * NN + j0]);
    float4 l;
    l.x = -0.5f * di * dj.x * w.x;
    l.y = -0.5f * di * dj.y * w.y;
    l.z = -0.5f * di * dj.z * w.z;
    l.w = -0.5f * di * dj.w * w.w;
    int dd = i - j0;
    if (dd == 0) l.x -= 0.5f;
    else if (dd == 1) l.y -= 0.5f;
    else if (dd == 2) l.z -= 0.5f;
    else if (dd == 3) l.w -= 0.5f;
    reinterpret_cast<float4*>(A)[idx] = l;
  }
}

// ---------------------------------------------------------------------------
// acc = h @ W0  (the k=0 term, overwrite).  RB=64 rows per block.
// ---------------------------------------------------------------------------
template <int F, int G>
__global__ __launch_bounds__(256) void acc0_gemm(const float* __restrict__ h,
                                                 const float* __restrict__ W0,
                                                 float* __restrict__ acc) {
  constexpr int RB = 64;
  constexpr int TGN = G / 16;
  __shared__ float Hs[RB][F + 1];
  __shared__ float Ws[F][G];
  const int tid = threadIdx.x;
  const size_t row0 = (size_t)blockIdx.x * RB;
  for (int idx = tid; idx < RB * F; idx += 256)
    Hs[idx / F][idx % F] = h[row0 * F + idx];
  for (int idx = tid; idx < F * G; idx += 256)
    Ws[idx / G][idx % G] = W0[idx];
  __syncthreads();
  const int tx = tid % 16, ty = tid / 16;
  float o[4][TGN];
#pragma unroll
  for (int r = 0; r < 4; ++r)
#pragma unroll
    for (int c = 0; c < TGN; ++c) o[r][c] = 0.f;
#pragma unroll 4
  for (int f = 0; f < F; ++f) {
    float a[4];
#pragma unroll
    for (int r = 0; r < 4; ++r) a[r] = Hs[ty * 4 + r][f];
#pragma unroll
    for (int c = 0; c < TGN; ++c) {
      float w = Ws[f][tx * TGN + c];
#pragma unroll
      for (int r = 0; r < 4; ++r) o[r][c] = fmaf(a[r], w, o[r][c]);
    }
  }
#pragma unroll
  for (int r = 0; r < 4; ++r) {
    size_t base = (row0 + ty * 4 + r) * G + tx * TGN;
#pragma unroll
    for (int c = 0; c < TGN; ++c) acc[base + c] = o[r][c];
  }
}

// ---------------------------------------------------------------------------
// Layer-1 recursion (F=3), fp32 path (L fp32 lives in A).
// ---------------------------------------------------------------------------
__global__ __launch_bounds__(256) void cheb_l1(
    const float* __restrict__ Lg, const float* __restrict__ Tprev,
    const float* __restrict__ Tpp, float* __restrict__ Tk,
    const float* __restrict__ Wk, float* __restrict__ acc, float alpha,
    float beta) {
  __shared__ float Ts[NN * 3];
  __shared__ float tkv[16][4];
  const int b = blockIdx.y;
  const int i0 = blockIdx.x * 16;
  const int tid = threadIdx.x;
  const float* tpb = &Tprev[(size_t)b * NN * 3];
  for (int idx = tid; idx < 768; idx += 256)
    *reinterpret_cast<float4*>(&Ts[idx * 4]) =
        *reinterpret_cast<const float4*>(&tpb[idx * 4]);
  __syncthreads();
  const int wv = tid >> 6, ln = tid & 63;
#pragma unroll
  for (int r = 0; r < 4; ++r) {
    const int i = i0 + wv * 4 + r;
    const float* Lrow = &Lg[((size_t)b << 20) + (size_t)i * NN];
    float a0 = 0.f, a1 = 0.f, a2 = 0.f;
#pragma unroll
    for (int c = 0; c < 16; ++c) {
      int j = c * 64 + ln;
      float w = Lrow[j];
      a0 = fmaf(w, Ts[j * 3 + 0], a0);
      a1 = fmaf(w, Ts[j * 3 + 1], a1);
      a2 = fmaf(w, Ts[j * 3 + 2], a2);
    }
#pragma unroll
    for (int off = 32; off; off >>= 1) {
      a0 += __shfl_down(a0, off, 64);
      a1 += __shfl_down(a1, off, 64);
      a2 += __shfl_down(a2, off, 64);
    }
    if (ln == 0) {
      const size_t rbase = (size_t)(b * NN + i) * 3;
      float t0 = alpha * a0, t1 = alpha * a1, t2 = alpha * a2;
      if (beta != 0.f) {
        t0 = fmaf(beta, Tpp[rbase + 0], t0);
        t1 = fmaf(beta, Tpp[rbase + 1], t1);
        t2 = fmaf(beta, Tpp[rbase + 2], t2);
      }
      Tk[rbase + 0] = t0;
      Tk[rbase + 1] = t1;
      Tk[rbase + 2] = t2;
      tkv[wv * 4 + r][0] = t0;
      tkv[wv * 4 + r][1] = t1;
      tkv[wv * 4 + r][2] = t2;
    }
  }
  __syncthreads();
  for (int idx = tid; idx < 16 * 32; idx += 256) {
    int rr = idx >> 5, cc = idx & 31;
    float v = tkv[rr][0] * Wk[cc] + tkv[rr][1] * Wk[32 + cc] +
              tkv[rr][2] * Wk[64 + cc];
    acc[(size_t)(b * NN + i0 + rr) * 32 + cc] += v;
  }
}

// ---------------------------------------------------------------------------
// transpose_split: h fp32 [B][NN][F] -> T^T hi/lo bf16 [B][F][NN]
// ---------------------------------------------------------------------------
template <int F>
__global__ __launch_bounds__(256) void transpose_split(
    const float* __restrict__ h, unsigned short* __restrict__ Th,
    unsigned short* __restrict__ Tl) {
  __shared__ float Ts[64][F + 1];
  const int b = blockIdx.y;
  const int m0 = blockIdx.x * 64;
  const int tid = threadIdx.x;
  for (int idx = tid; idx < 64 * (F / 4); idx += 256) {
    int row = idx / (F / 4), c4 = idx % (F / 4);
    float4 v = *reinterpret_cast<const float4*>(
        &h[((size_t)(b * NN + m0 + row)) * F + c4 * 4]);
    Ts[row][c4 * 4 + 0] = v.x;
    Ts[row][c4 * 4 + 1] = v.y;
    Ts[row][c4 * 4 + 2] = v.z;
    Ts[row][c4 * 4 + 3] = v.w;
  }
  __syncthreads();
  for (int idx = tid; idx < F * 64; idx += 256) {
    int f = idx >> 6, row = idx & 63;
    float t = Ts[row][f];
    unsigned short hi = f2bf(t);
    unsigned short lo = f2bf(t - bf2f(hi));
    size_t g = ((size_t)(b * F + f)) * NN + m0 + row;
    Th[g] = hi;
    Tl[g] = lo;
  }
}

// ---------------------------------------------------------------------------
// MFMA recursion step: S = L @ Tprev  (bf16x4 split-product, fp32-accurate)
// Tk = alpha*S + beta*Tpp; writes Tk fp32, Tk^T hi/lo bf16, acc += Tk @ Wk.
// Block: 256 thr / 4 waves; 64 M-rows per block; 1D grid 512, XCD-swizzled.
// ---------------------------------------------------------------------------
template <int F, int G>
__global__ __launch_bounds__(256) void cheb_mfma(
    const float* __restrict__ Lg, const unsigned short* __restrict__ Tth,
    const unsigned short* __restrict__ Ttl, const float* __restrict__ Tpp,
    float* __restrict__ Tk, unsigned short* __restrict__ Toh,
    unsigned short* __restrict__ Tol, const float* __restrict__ Wk,
    float* __restrict__ acc, float alpha, float beta) {
  constexpr int NC = F / 16;       // 16-col tiles of T
  constexpr int TGN = G / 16;
  __shared__ float Ts[64][F + 1];
  __shared__ float Ws[F][G];
  const int tid = threadIdx.x;

  // XCD-aware swizzle: batch b's 16 M-tiles land on one XCD (L panel = 4MB = L2)
  int id = blockIdx.x;
  int xcd = id & 7;
  int t2 = id >> 3;
  int mt = t2 & 15;
  int b = xcd + 8 * (t2 >> 4);
  const int m0 = mt * 64;

  // stage Wk
  for (int idx = tid; idx < F * G / 4; idx += 256) {
    int r = idx / (G / 4), c4 = idx % (G / 4);
    *reinterpret_cast<float4*>(&Ws[r][c4 * 4]) =
        *reinterpret_cast<const float4*>(&Wk[r * G + c4 * 4]);
  }

  const int wv = tid >> 6, ln = tid & 63;
  const int arow = ln & 15;        // A row within 16 / B col within 16
  const int kg = ln >> 4;          // k-group (0..3), 8 consecutive k each
  const int wm = m0 + wv * 16;

  f32x4 accv[NC];
#pragma unroll
  for (int c = 0; c < NC; ++c) accv[c] = {0.f, 0.f, 0.f, 0.f};

  const float* Arow = &Lg[((size_t)b << 20) + (size_t)(wm + arow) * NN + kg * 8];
  const unsigned short* Bh = &Tth[((size_t)(b * F) + arow) * NN + kg * 8];
  const unsigned short* Bl = &Ttl[((size_t)(b * F) + arow) * NN + kg * 8];

  for (int k0 = 0; k0 < NN; k0 += 32) {
    float4 a0 = *reinterpret_cast<const float4*>(Arow + k0);
    float4 a1 = *reinterpret_cast<const float4*>(Arow + k0 + 4);
    float av[8] = {a0.x, a0.y, a0.z, a0.w, a1.x, a1.y, a1.z, a1.w};
    s16x8 ah, al;
#pragma unroll
    for (int j = 0; j < 8; ++j) {
      unsigned short hi = f2bf(av[j]);
      ah[j] = (short)hi;
      al[j] = (short)f2bf(av[j] - bf2f(hi));
    }
#pragma unroll
    for (int c = 0; c < NC; ++c) {
      s16x8 bh = *reinterpret_cast<const s16x8*>(&Bh[(size_t)c * 16 * NN + k0]);
      s16x8 bl = *reinterpret_cast<const s16x8*>(&Bl[(size_t)c * 16 * NN + k0]);
      accv[c] = __builtin_amdgcn_mfma_f32_16x16x32_bf16(ah, bh, accv[c], 0, 0, 0);
      accv[c] = __builtin_amdgcn_mfma_f32_16x16x32_bf16(al, bh, accv[c], 0, 0, 0);
      accv[c] = __builtin_amdgcn_mfma_f32_16x16x32_bf16(ah, bl, accv[c], 0, 0, 0);
      accv[c] = __builtin_amdgcn_mfma_f32_16x16x32_bf16(al, bl, accv[c], 0, 0, 0);
    }
  }

  // C layout: col = ln&15, row = (ln>>4)*4 + r  (m89-verified)
#pragma unroll
  for (int c = 0; c < NC; ++c)
#pragma unroll
    for (int r = 0; r < 4; ++r)
      Ts[wv * 16 + kg * 4 + r][c * 16 + arow] = accv[c][r];
  __syncthreads();

  // Tk = alpha*S + beta*Tpp; write fp32 Tk; update Ts in place
  const bool hasB = (beta != 0.f);
  for (int idx = tid; idx < 64 * (F / 4); idx += 256) {
    int row = idx / (F / 4), f0 = (idx % (F / 4)) * 4;
    size_t g = ((size_t)(b * NN + m0 + row)) * F + f0;
    float t0 = alpha * Ts[row][f0 + 0];
    float t1 = alpha * Ts[row][f0 + 1];
    float t2 = alpha * Ts[row][f0 + 2];
    float t3 = alpha * Ts[row][f0 + 3];
    if (hasB) {
      float4 p = *reinterpret_cast<const float4*>(&Tpp[g]);
      t0 = fmaf(beta, p.x, t0);
      t1 = fmaf(beta, p.y, t1);
      t2 = fmaf(beta, p.z, t2);
      t3 = fmaf(beta, p.w, t3);
    }
    float4 tv = {t0, t1, t2, t3};
    *reinterpret_cast<float4*>(&Tk[g]) = tv;
    Ts[row][f0 + 0] = t0;
    Ts[row][f0 + 1] = t1;
    Ts[row][f0 + 2] = t2;
    Ts[row][f0 + 3] = t3;
  }
  __syncthreads();

  // transposed bf16 hi/lo for next step's B operand
  for (int idx = tid; idx < F * 64; idx += 256) {
    int f = idx >> 6, row = idx & 63;
    float t = Ts[row][f];
    unsigned short hi = f2bf(t);
    unsigned short lo = f2bf(t - bf2f(hi));
    size_t g = ((size_t)(b * F + f)) * NN + m0 + row;
    Toh[g] = hi;
    Tol[g] = lo;
  }

  // fused epilogue: acc += Tk @ Wk
  const int tx = tid & 15, ty = tid >> 4;
  float o[4][TGN];
#pragma unroll
  for (int r = 0; r < 4; ++r)
#pragma unroll
    for (int c = 0; c < TGN; ++c) o[r][c] = 0.f;
#pragma unroll 8
  for (int f = 0; f < F; ++f) {
    float a[4];
#pragma unroll
    for (int r = 0; r < 4; ++r) a[r] = Ts[ty * 4 + r][f];
#pragma unroll
    for (int c = 0; c < TGN; ++c) {
      float w = Ws[f][tx * TGN + c];
#pragma unroll
      for (int r = 0; r < 4; ++r) o[r][c] = fmaf(a[r], w, o[r][c]);
    }
  }
#pragma unroll
  for (int r = 0; r < 4; ++r) {
    size_t base = ((size_t)(b * NN + m0 + ty * 4 + r)) * G + tx * TGN;
    float4 v = *reinterpret_cast<const float4*>(&acc[base]);
    v.x += o[r][0];
    v.y += o[r][1];
    v.z += o[r][2];
    v.w += o[r][3];
    *reinterpret_cast<float4*>(&acc[base]) = v;
  }
}

// ---------------------------------------------------------------------------
// Fallback fused fp32 recursion GEMM (round-2 proven path)
// ---------------------------------------------------------------------------
template <int BM, int F, int G>
__global__ __launch_bounds__(256) void cheb_gemm(
    const float* __restrict__ Lg, const float* __restrict__ Tprev,
    const float* __restrict__ Tpp, float* __restrict__ Tk,
    const float* __restrict__ Wk, float* __restrict__ acc, float alpha,
    float beta) {
  constexpr int BK = 32;
  constexpr int TM = 4, TN = 4;
  constexpr int NTX = F / TN;
  constexpr int NTY = BM / TM;
  static_assert(NTX * NTY == 256, "tile mismatch");
  constexpr int TGN = G / NTX;

  __shared__ float As[BM][BK + 1];
  __shared__ float Bs[BK][F];
  __shared__ float Ws[F][G];
  __shared__ float Ts[BM][F + 1];

  const int tid = threadIdx.x;
  const int tx = tid % NTX, ty = tid / NTX;
  const int b = blockIdx.y;
  const int i0 = blockIdx.x * BM;

  constexpr int W_ITERS = (F * G / 4) / 256;
#pragma unroll
  for (int it = 0; it < W_ITERS; ++it) {
    int idx = tid + it * 256;
    int r = idx / (G / 4), c4 = idx % (G / 4);
    float4 v = *reinterpret_cast<const float4*>(&Wk[r * G + c4 * 4]);
    *reinterpret_cast<float4*>(&Ws[r][c4 * 4]) = v;
  }

  float accT[TM][TN];
#pragma unroll
  for (int r = 0; r < TM; ++r)
#pragma unroll
    for (int c = 0; c < TN; ++c) accT[r][c] = 0.f;

  const size_t Lbase = ((size_t)b << 20);
  constexpr int A_ITERS = (BM * (BK / 4)) / 256;
  constexpr int B_ITERS = (BK * (F / 4) + 255) / 256;

  for (int k0 = 0; k0 < NN; k0 += BK) {
#pragma unroll
    for (int it = 0; it < A_ITERS; ++it) {
      int idx = tid + it * 256;
      int m = idx >> 3, k4 = idx & 7;
      float4 v = *reinterpret_cast<const float4*>(
          &Lg[Lbase + (size_t)(i0 + m) * NN + k0 + k4 * 4]);
      As[m][k4 * 4 + 0] = v.x;
      As[m][k4 * 4 + 1] = v.y;
      As[m][k4 * 4 + 2] = v.z;
      As[m][k4 * 4 + 3] = v.w;
    }
#pragma unroll
    for (int it = 0; it < B_ITERS; ++it) {
      int idx = tid + it * 256;
      int kr = idx / (F / 4), c4 = idx % (F / 4);
      float4 v = *reinterpret_cast<const float4*>(
          &Tprev[(size_t)(b * NN + k0 + kr) * F + c4 * 4]);
      *reinterpret_cast<float4*>(&Bs[kr][c4 * 4]) = v;
    }
    __syncthreads();
#pragma unroll
    for (int kk = 0; kk < BK; ++kk) {
      float a[TM];
#pragma unroll
      for (int r = 0; r < TM; ++r) a[r] = As[ty * TM + r][kk];
      float4 bv = *reinterpret_cast<const float4*>(&Bs[kk][tx * TN]);
      float bb[4] = {bv.x, bv.y, bv.z, bv.w};
#pragma unroll
      for (int r = 0; r < TM; ++r)
#pragma unroll
        for (int c = 0; c < TN; ++c)
          accT[r][c] = fmaf(a[r], bb[c], accT[r][c]);
    }
    __syncthreads();
  }

  const bool hasB = (beta != 0.f);
#pragma unroll
  for (int r = 0; r < TM; ++r) {
    int row = i0 + ty * TM + r;
    size_t gidx = (size_t)(b * NN + row) * F + tx * TN;
    float t0 = alpha * accT[r][0], t1 = alpha * accT[r][1];
    float t2 = alpha * accT[r][2], t3 = alpha * accT[r][3];
    if (hasB) {
      float4 p = *reinterpret_cast<const float4*>(&Tpp[gidx]);
      t0 = fmaf(beta, p.x, t0);
      t1 = fmaf(beta, p.y, t1);
      t2 = fmaf(beta, p.z, t2);
      t3 = fmaf(beta, p.w, t3);
    }
    float4 tv = {t0, t1, t2, t3};
    *reinterpret_cast<float4*>(&Tk[gidx]) = tv;
    Ts[ty * TM + r][tx * TN + 0] = t0;
    Ts[ty * TM + r][tx * TN + 1] = t1;
    Ts[ty * TM + r][tx * TN + 2] = t2;
    Ts[ty * TM + r][tx * TN + 3] = t3;
  }
  __syncthreads();

  float oacc[TM][TGN];
#pragma unroll
  for (int r = 0; r < TM; ++r)
#pragma unroll
    for (int c = 0; c < TGN; ++c) oacc[r][c] = 0.f;
#pragma unroll 8
  for (int f = 0; f < F; ++f) {
    float a[TM];
#pragma unroll
    for (int r = 0; r < TM; ++r) a[r] = Ts[ty * TM + r][f];
#pragma unroll
    for (int c = 0; c < TGN; ++c) {
      float w = Ws[f][tx * TGN + c];
#pragma unroll
      for (int r = 0; r < TM; ++r) oacc[r][c] = fmaf(a[r], w, oacc[r][c]);
    }
  }
#pragma unroll
  for (int r = 0; r < TM; ++r) {
    int row = i0 + ty * TM + r;
    size_t base = (size_t)(b * NN + row) * G + tx * TGN;
#pragma unroll
    for (int c = 0; c < TGN; ++c) acc[base + c] += oacc[r][c];
  }
}

// ---------------------------------------------------------------------------
// BatchNorm (train, biased var) + ELU
// ---------------------------------------------------------------------------
constexpr int BN_BLOCKS = 256;

template <int C>
__global__ __launch_bounds__(256) void bn_part(const float* __restrict__ acc,
                                               double* __restrict__ part) {
  constexpr int GR = 256 / C;
  const int tid = threadIdx.x;
  const int c = tid % C;
  const int g = tid / C;
  double s = 0.0, s2 = 0.0;
  for (int r = blockIdx.x * GR + g; r < ROWS; r += BN_BLOCKS * GR) {
    double v = (double)acc[(size_t)r * C + c];
    s += v;
    s2 += v * v;
  }
  __shared__ double Ls[256], Ls2[256];
  Ls[tid] = s;
  Ls2[tid] = s2;
  __syncthreads();
  for (int str = 128; str >= C; str >>= 1) {
    if (tid < str) {
      Ls[tid] += Ls[tid + str];
      Ls2[tid] += Ls2[tid + str];
    }
    __syncthreads();
  }
  if (tid < C) {
    part[(size_t)blockIdx.x * 2 * C + tid] = Ls[tid];
    part[(size_t)blockIdx.x * 2 * C + C + tid] = Ls2[tid];
  }
}

template <int C>
__global__ void bn_final(const double* __restrict__ part,
                         const float* __restrict__ g,
                         const float* __restrict__ be,
                         float* __restrict__ sc) {
  int t = threadIdx.x;
  if (t < C) {
    double s = 0.0, s2 = 0.0;
    for (int b = 0; b < BN_BLOCKS; ++b) {
      s += part[(size_t)b * 2 * C + t];
      s2 += part[(size_t)b * 2 * C + C + t];
    }
    double mu = s / ROWS;
    double var = s2 / ROWS - mu * mu;
    float scale = g[t] / sqrtf((float)var + 1e-5f);
    sc[t] = scale;
    sc[C + t] = be[t] - (float)mu * scale;
  }
}

template <int C>
__global__ __launch_bounds__(256) void bn_apply_elu(
    const float* __restrict__ acc, const float* __restrict__ sc,
    float* __restrict__ h) {
  const long total4 = (long)ROWS * C / 4;
  for (long idx = (long)blockIdx.x * 256 + threadIdx.x; idx < total4;
       idx += (long)gridDim.x * 256) {
    long base = idx * 4;
    int c0 = (int)(base % C);
    float4 v = reinterpret_cast<const float4*>(acc)[idx];
    float t0 = fmaf(v.x, sc[c0 + 0], sc[C + c0 + 0]);
    float t1 = fmaf(v.y, sc[c0 + 1], sc[C + c0 + 1]);
    float t2 = fmaf(v.z, sc[c0 + 2], sc[C + c0 + 2]);
    float t3 = fmaf(v.w, sc[c0 + 3], sc[C + c0 + 3]);
    float4 o;
    o.x = t0 > 0.f ? t0 : expm1f(t0);
    o.y = t1 > 0.f ? t1 : expm1f(t1);
    o.z = t2 > 0.f ? t2 : expm1f(t2);
    o.w = t3 > 0.f ? t3 : expm1f(t3);
    reinterpret_cast<float4*>(h)[idx] = o;
  }
}

// ---------------------------------------------------------------------------
__global__ __launch_bounds__(256) void final_k(const float* __restrict__ h,
                                               const float* __restrict__ Wfc,
                                               const float* __restrict__ bfc,
                                               float* __restrict__ out) {
  const int b = blockIdx.x;
  const int tid = threadIdx.x;
  const int c = tid % 64;
  const int g = tid / 64;
  float s = 0.f;
  for (int r = g; r < NN; r += 4) s += h[(size_t)(b * NN + r) * 64 + c];
  __shared__ float red[256];
  red[tid] = s;
  __syncthreads();
  if (tid < 128) red[tid] += red[tid + 128];
  __syncthreads();
  if (tid < 64) {
    float pooled = (red[tid] + red[tid + 64]) * (1.0f / 1024.0f);
    float v = pooled * Wfc[tid];
#pragma unroll
    for (int off = 32; off; off >>= 1) v += __shfl_down(v, off, 64);
    if (tid == 0) out[b] = v + bfc[0];
  }
}

// ---------------------------------------------------------------------------
extern "C" void kernel_launch(void* const* d_in, const int* in_sizes, int n_in,
                              void* d_out, int out_size, void* d_ws,
                              size_t ws_size, hipStream_t stream) {
  const float* x = (const float*)d_in[0];
  float* A = (float*)d_in[1];  // overwritten in place with L
  const float* W1 = (const float*)d_in[2];
  const float* g1 = (const float*)d_in[4];
  const float* be1 = (const float*)d_in[5];
  const float* W2 = (const float*)d_in[6];
  const float* g2 = (const float*)d_in[8];
  const float* be2 = (const float*)d_in[9];
  const float* W3 = (const float*)d_in[10];
  const float* g3 = (const float*)d_in[12];
  const float* be3 = (const float*)d_in[13];
  const float* Wfc = (const float*)d_in[14];
  const float* bfc = (const float*)d_in[15];

  constexpr size_t TBUF = 2097152;   // 32768*64 floats
  float* wsf = (float*)d_ws;
  float* buf0 = wsf;
  float* buf1 = buf0 + TBUF;
  float* buf2 = buf1 + TBUF;
  float* acc = buf2 + TBUF;
  // T^T bf16 hi/lo ping-pong (each 32*64*1024 u16 = 4MB)
  unsigned short* tt = (unsigned short*)(acc + TBUF);
  unsigned short* TTh[2] = {tt, tt + 2 * 2097152};
  unsigned short* TTl[2] = {tt + 2097152, tt + 3 * 2097152};
  float* S = wsf + 8388608 + 4194304;
  float* D = S + (size_t)NSLICE * ROWS;
  double* part_m = (double*)(D + ROWS);
  float* sc_m = (float*)(part_m + (size_t)BN_BLOCKS * 2 * 64);
  size_t need_m = (size_t)((sc_m + 128) - wsf) * sizeof(float);

  // fallback layout (no tt region)
  float* S_f = wsf + 8388608;
  float* D_f = S_f + (size_t)NSLICE * ROWS;
  double* part_f = (double*)(D_f + ROWS);
  float* sc_f = (float*)(part_f + (size_t)BN_BLOCKS * 2 * 64);
  size_t need_f = (size_t)((sc_f + 128) - wsf) * sizeof(float);

  const bool use_m = (ws_size >= need_m);
  if (!use_m && ws_size < need_f) return;
  float* Sp = use_m ? S : S_f;
  float* Dp = use_m ? D : D_f;
  double* part = use_m ? part_m : part_f;
  float* sc = use_m ? sc_m : sc_f;

  float* bufs[3] = {buf0, buf1, buf2};

  // ---- Laplacian (in place over A) ----
  colsum_w<<<dim3(4, NSLICE, NB), 256, 0, stream>>>(A, x, Sp);
  d_kernel<<<128, 256, 0, stream>>>(Sp, Dp);
  scale_L<<<4096, 256, 0, stream>>>(A, Dp);

  // ---- layer 1: F=3 -> G=32, input x (fp32 path) ----
  acc0_gemm<3, 32><<<512, 256, 0, stream>>>(x, W1, acc);
  {
    const float* Tm1 = x;
    const float* Tm2 = nullptr;
    for (int k = 1; k <= 8; ++k) {
      float* outb = bufs[k % 3];
      float alpha = (k == 1) ? 1.f : 2.f;
      float beta = (k == 1) ? 0.f : -1.f;
      cheb_l1<<<dim3(64, NB), 256, 0, stream>>>(
          A, Tm1, (k == 1) ? x : Tm2, outb, W1 + k * 3 * 32, acc, alpha, beta);
      Tm2 = Tm1;
      Tm1 = outb;
    }
  }
  bn_part<32><<<BN_BLOCKS, 256, 0, stream>>>(acc, part);
  bn_final<32><<<1, 64, 0, stream>>>(part, g1, be1, sc);
  bn_apply_elu<32><<<1024, 256, 0, stream>>>(acc, sc, buf0);  // h1 -> buf0

  // ---- layer 2: F=32 -> G=64 ----
  acc0_gemm<32, 64><<<512, 256, 0, stream>>>(buf0, W2, acc);
  if (use_m) {
    transpose_split<32><<<dim3(16, NB), 256, 0, stream>>>(buf0, TTh[0], TTl[0]);
    const float* Tm1 = buf0;
    const float* Tm2 = nullptr;
    for (int k = 1; k <= 8; ++k) {
      float* outb = bufs[k % 3];
      int si = (k - 1) & 1, so = k & 1;
      float alpha = (k == 1) ? 1.f : 2.f;
      float beta = (k == 1) ? 0.f : -1.f;
      cheb_mfma<32, 64><<<512, 256, 0, stream>>>(
          A, TTh[si], TTl[si], (k == 1) ? buf0 : Tm2, outb, TTh[so], TTl[so],
          W2 + k * 32 * 64, acc, alpha, beta);
      Tm2 = Tm1;
      Tm1 = outb;
    }
  } else {
    const float* Tm1 = buf0;
    const float* Tm2 = nullptr;
    for (int k = 1; k <= 8; ++k) {
      float* outb = bufs[k % 3];
      float alpha = (k == 1) ? 1.f : 2.f;
      float beta = (k == 1) ? 0.f : -1.f;
      cheb_gemm<128, 32, 64><<<dim3(8, NB), 256, 0, stream>>>(
          A, Tm1, (k == 1) ? buf0 : Tm2, outb, W2 + k * 32 * 64, acc, alpha,
          beta);
      Tm2 = Tm1;
      Tm1 = outb;
    }
  }
  bn_part<64><<<BN_BLOCKS, 256, 0, stream>>>(acc, part);
  bn_final<64><<<1, 64, 0, stream>>>(part, g2, be2, sc);
  bn_apply_elu<64><<<2048, 256, 0, stream>>>(acc, sc, buf0);  // h2 -> buf0

  // ---- layer 3: F=64 -> G=64 ----
  acc0_gemm<64, 64><<<512, 256, 0, stream>>>(buf0, W3, acc);
  if (use_m) {
    transpose_split<64><<<dim3(16, NB), 256, 0, stream>>>(buf0, TTh[0], TTl[0]);
    const float* Tm1 = buf0;
    const float* Tm2 = nullptr;
    for (int k = 1; k <= 8; ++k) {
      float* outb = bufs[k % 3];
      int si = (k - 1) & 1, so = k & 1;
      float alpha = (k == 1) ? 1.f : 2.f;
      float beta = (k == 1) ? 0.f : -1.f;
      cheb_mfma<64, 64><<<512, 256, 0, stream>>>(
          A, TTh[si], TTl[si], (k == 1) ? buf0 : Tm2, outb, TTh[so], TTl[so],
          W3 + k * 64 * 64, acc, alpha, beta);
      Tm2 = Tm1;
      Tm1 = outb;
    }
  } else {
    const float* Tm1 = buf0;
    const float* Tm2 = nullptr;
    for (int k = 1; k <= 8; ++k) {
      float* outb = bufs[k % 3];
      float alpha = (k == 1) ? 1.f : 2.f;
      float beta = (k == 1) ? 0.f : -1.f;
      cheb_gemm<64, 64, 64><<<dim3(16, NB), 256, 0, stream>>>(
          A, Tm1, (k == 1) ? buf0 : Tm2, outb, W3 + k * 64 * 64, acc, alpha,
          beta);
      Tm2 = Tm1;
      Tm1 = outb;
    }
  }
  bn_part<64><<<BN_BLOCKS, 256, 0, stream>>>(acc, part);
  bn_final<64><<<1, 64, 0, stream>>>(part, g3, be3, sc);
  bn_apply_elu<64><<<2048, 256, 0, stream>>>(acc, sc, buf0);  // h3 -> buf0

  // ---- head ----
  final_k<<<NB, 256, 0, stream>>>(buf0, Wfc, bfc, (float*)d_out);
}

// Round 6
// 1216.603 us; speedup vs baseline: 1.3732x; 1.3732x over previous
//
#include <hip/hip_runtime.h>
#include <hip/hip_bf16.h>
#include <math.h>

constexpr int NN = 1024;          // nodes
constexpr int NB = 32;            // batch
constexpr int ROWS = NB * NN;     // 32768 rows for BN
constexpr int NSLICE = 8;         // colsum partial slices (deterministic)

using f32x4 = __attribute__((ext_vector_type(4))) float;
using s16x8 = __attribute__((ext_vector_type(8))) short;   // 8 bf16
using us8 = __attribute__((ext_vector_type(8))) unsigned short;

__device__ inline unsigned short f2bf(float f) {
  unsigned u = __float_as_uint(f);
  unsigned r = (u + 0x7FFFu + ((u >> 16) & 1u)) >> 16;  // RTNE
  return (unsigned short)r;
}
__device__ inline float bf2f(unsigned short h) {
  return __uint_as_float((unsigned)h << 16);
}

// ---------------------------------------------------------------------------
// Laplacian pass 1: W = A/(dist+1e-3) in place; partial colsums (no atomics)
// ---------------------------------------------------------------------------
__global__ __launch_bounds__(256) void colsum_w(float* __restrict__ A,
                                                const float* __restrict__ x,
                                                float* __restrict__ S) {
  const int b = blockIdx.z;
  const int j = blockIdx.x * 256 + threadIdx.x;
  const int slice = blockIdx.y;
  const int ibase = slice * 128;
  __shared__ float xs[128 * 3];
  for (int idx = threadIdx.x; idx < 384; idx += 256)
    xs[idx] = x[(size_t)(b * NN + ibase) * 3 + idx];
  const float xj0 = x[(size_t)(b * NN + j) * 3 + 0];
  const float xj1 = x[(size_t)(b * NN + j) * 3 + 1];
  const float xj2 = x[(size_t)(b * NN + j) * 3 + 2];
  __syncthreads();
  float s = 0.f;
  size_t off = ((size_t)b << 20) + (size_t)ibase * NN + j;
  for (int ii = 0; ii < 128; ++ii, off += NN) {
    float a = A[off];
    float dx = xj0 - xs[ii * 3 + 0];
    float dy = xj1 - xs[ii * 3 + 1];
    float dz = xj2 - xs[ii * 3 + 2];
    float dist = sqrtf(dx * dx + dy * dy + dz * dz);
    float w = a / (dist + 0.001f);
    A[off] = w;
    s += w;
  }
  S[(size_t)slice * ROWS + b * NN + j] = s;
}

__global__ __launch_bounds__(256) void d_kernel(const float* __restrict__ S,
                                                float* __restrict__ D) {
  int i = blockIdx.x * 256 + threadIdx.x;
  if (i < ROWS) {
    float s = 0.f;
#pragma unroll
    for (int p = 0; p < NSLICE; ++p) s += S[(size_t)p * ROWS + i];
    D[i] = 1.f / sqrtf(s);
  }
}

// ---------------------------------------------------------------------------
// pack_L: L = -0.5*d_i*W*d_j - 0.5*I  -> fp32 in place (for layer1/fallback)
// AND packed bf16 hi/lo, fragment-major: [b][rb=row/16][kt=col/32][lane*8+j]
// lane = ((col>>3)&3)*16 + (row&15)   (MFMA A-fragment order)
// ---------------------------------------------------------------------------
__global__ __launch_bounds__(256) void pack_L(float* __restrict__ A,
                                              const float* __restrict__ D,
                                              unsigned short* __restrict__ Lh,
                                              unsigned short* __restrict__ Ll) {
  const int b = blockIdx.y;
  const int rb = blockIdx.x;           // 64 row-blocks of 16
  const int i0 = rb * 16;
  const float* Db = &D[b * NN];
  for (int ci = threadIdx.x; ci < 2048; ci += 256) {
    int kt = ci >> 6, l = ci & 63;
    int r = l & 15, kg = l >> 4;
    int i = i0 + r;
    int j0 = kt * 32 + kg * 8;
    size_t ga = ((size_t)b << 20) + (size_t)i * NN + j0;
    float4 w0 = *reinterpret_cast<const float4*>(&A[ga]);
    float4 w1 = *reinterpret_cast<const float4*>(&A[ga + 4]);
    float di = Db[i];
    float4 d0 = *reinterpret_cast<const float4*>(&Db[j0]);
    float4 d1 = *reinterpret_cast<const float4*>(&Db[j0 + 4]);
    float lv[8];
    lv[0] = -0.5f * di * d0.x * w0.x;
    lv[1] = -0.5f * di * d0.y * w0.y;
    lv[2] = -0.5f * di * d0.z * w0.z;
    lv[3] = -0.5f * di * d0.w * w0.w;
    lv[4] = -0.5f * di * d1.x * w1.x;
    lv[5] = -0.5f * di * d1.y * w1.y;
    lv[6] = -0.5f * di * d1.z * w1.z;
    lv[7] = -0.5f * di * d1.w * w1.w;
    int dd = i - j0;
    if (dd >= 0 && dd < 8) lv[dd] -= 0.5f;
    float4 o0 = {lv[0], lv[1], lv[2], lv[3]};
    float4 o1 = {lv[4], lv[5], lv[6], lv[7]};
    *reinterpret_cast<float4*>(&A[ga]) = o0;
    *reinterpret_cast<float4*>(&A[ga + 4]) = o1;
    us8 vh, vl;
#pragma unroll
    for (int jj = 0; jj < 8; ++jj) {
      unsigned short hi = f2bf(lv[jj]);
      vh[jj] = hi;
      vl[jj] = f2bf(lv[jj] - bf2f(hi));
    }
    size_t po = (((size_t)b * 64 + rb) * 32 + kt) * 512 + (size_t)l * 8;
    *reinterpret_cast<us8*>(&Lh[po]) = vh;
    *reinterpret_cast<us8*>(&Ll[po]) = vl;
  }
}

// fallback scale_L (fp32 in place only)
__global__ __launch_bounds__(256) void scale_L(float* __restrict__ A,
                                               const float* __restrict__ D) {
  const long total4 = (long)NB * NN * NN / 4;
  for (long idx = (long)blockIdx.x * 256 + threadIdx.x; idx < total4;
       idx += (long)gridDim.x * 256) {
    long base = idx * 4;
    int j0 = (int)(base & (NN - 1));
    int i = (int)((base >> 10) & (NN - 1));
    int b = (int)(base >> 20);
    float4 w = reinterpret_cast<float4*>(A)[idx];
    float di = D[b * NN + i];
    float4 dj = *reinterpret_cast<const float4*>(&D[b * NN + j0]);
    float4 l;
    l.x = -0.5f * di * dj.x * w.x;
    l.y = -0.5f * di * dj.y * w.y;
    l.z = -0.5f * di * dj.z * w.z;
    l.w = -0.5f * di * dj.w * w.w;
    int dd = i - j0;
    if (dd == 0) l.x -= 0.5f;
    else if (dd == 1) l.y -= 0.5f;
    else if (dd == 2) l.z -= 0.5f;
    else if (dd == 3) l.w -= 0.5f;
    reinterpret_cast<float4*>(A)[idx] = l;
  }
}

// ---------------------------------------------------------------------------
// acc = h @ W0  (the k=0 term, overwrite).
// ---------------------------------------------------------------------------
template <int F, int G>
__global__ __launch_bounds__(256) void acc0_gemm(const float* __restrict__ h,
                                                 const float* __restrict__ W0,
                                                 float* __restrict__ acc) {
  constexpr int RB = 64;
  constexpr int TGN = G / 16;
  __shared__ float Hs[RB][F + 1];
  __shared__ float Ws[F][G];
  const int tid = threadIdx.x;
  const size_t row0 = (size_t)blockIdx.x * RB;
  for (int idx = tid; idx < RB * F; idx += 256)
    Hs[idx / F][idx % F] = h[row0 * F + idx];
  for (int idx = tid; idx < F * G; idx += 256)
    Ws[idx / G][idx % G] = W0[idx];
  __syncthreads();
  const int tx = tid % 16, ty = tid / 16;
  float o[4][TGN];
#pragma unroll
  for (int r = 0; r < 4; ++r)
#pragma unroll
    for (int c = 0; c < TGN; ++c) o[r][c] = 0.f;
#pragma unroll 4
  for (int f = 0; f < F; ++f) {
    float a[4];
#pragma unroll
    for (int r = 0; r < 4; ++r) a[r] = Hs[ty * 4 + r][f];
#pragma unroll
    for (int c = 0; c < TGN; ++c) {
      float w = Ws[f][tx * TGN + c];
#pragma unroll
      for (int r = 0; r < 4; ++r) o[r][c] = fmaf(a[r], w, o[r][c]);
    }
  }
#pragma unroll
  for (int r = 0; r < 4; ++r) {
    size_t base = (row0 + ty * 4 + r) * G + tx * TGN;
#pragma unroll
    for (int c = 0; c < TGN; ++c) acc[base + c] = o[r][c];
  }
}

// ---------------------------------------------------------------------------
// Layer-1 recursion (F=3), fp32 path (reads fp32 L in A).
// ---------------------------------------------------------------------------
__global__ __launch_bounds__(256) void cheb_l1(
    const float* __restrict__ Lg, const float* __restrict__ Tprev,
    const float* __restrict__ Tpp, float* __restrict__ Tk,
    const float* __restrict__ Wk, float* __restrict__ acc, float alpha,
    float beta) {
  __shared__ float Ts[NN * 3];
  __shared__ float tkv[16][4];
  const int b = blockIdx.y;
  const int i0 = blockIdx.x * 16;
  const int tid = threadIdx.x;
  const float* tpb = &Tprev[(size_t)b * NN * 3];
  for (int idx = tid; idx < 768; idx += 256)
    *reinterpret_cast<float4*>(&Ts[idx * 4]) =
        *reinterpret_cast<const float4*>(&tpb[idx * 4]);
  __syncthreads();
  const int wv = tid >> 6, ln = tid & 63;
#pragma unroll
  for (int r = 0; r < 4; ++r) {
    const int i = i0 + wv * 4 + r;
    const float* Lrow = &Lg[((size_t)b << 20) + (size_t)i * NN];
    float a0 = 0.f, a1 = 0.f, a2 = 0.f;
#pragma unroll
    for (int c = 0; c < 16; ++c) {
      int j = c * 64 + ln;
      float w = Lrow[j];
      a0 = fmaf(w, Ts[j * 3 + 0], a0);
      a1 = fmaf(w, Ts[j * 3 + 1], a1);
      a2 = fmaf(w, Ts[j * 3 + 2], a2);
    }
#pragma unroll
    for (int off = 32; off; off >>= 1) {
      a0 += __shfl_down(a0, off, 64);
      a1 += __shfl_down(a1, off, 64);
      a2 += __shfl_down(a2, off, 64);
    }
    if (ln == 0) {
      const size_t rbase = (size_t)(b * NN + i) * 3;
      float t0 = alpha * a0, t1 = alpha * a1, t2 = alpha * a2;
      if (beta != 0.f) {
        t0 = fmaf(beta, Tpp[rbase + 0], t0);
        t1 = fmaf(beta, Tpp[rbase + 1], t1);
        t2 = fmaf(beta, Tpp[rbase + 2], t2);
      }
      Tk[rbase + 0] = t0;
      Tk[rbase + 1] = t1;
      Tk[rbase + 2] = t2;
      tkv[wv * 4 + r][0] = t0;
      tkv[wv * 4 + r][1] = t1;
      tkv[wv * 4 + r][2] = t2;
    }
  }
  __syncthreads();
  for (int idx = tid; idx < 16 * 32; idx += 256) {
    int rr = idx >> 5, cc = idx & 31;
    float v = tkv[rr][0] * Wk[cc] + tkv[rr][1] * Wk[32 + cc] +
              tkv[rr][2] * Wk[64 + cc];
    acc[(size_t)(b * NN + i0 + rr) * 32 + cc] += v;
  }
}

// ---------------------------------------------------------------------------
// pack_T: h fp32 [B][NN][F] -> packed B-operand hi/lo
// [b][ft=f/16][kt=n/32][lane*8+j], lane = ((n>>3)&3)*16 + (f&15)
// ---------------------------------------------------------------------------
template <int FT>
__global__ __launch_bounds__(256) void pack_T(const float* __restrict__ h,
                                              unsigned short* __restrict__ Oh,
                                              unsigned short* __restrict__ Ol) {
  constexpr int F = FT * 16;
  __shared__ float Ts[64][F + 1];
  const int b = blockIdx.y;
  const int m0 = blockIdx.x * 64;
  const int tid = threadIdx.x;
  for (int idx = tid; idx < 64 * (F / 4); idx += 256) {
    int row = idx / (F / 4), c4 = idx % (F / 4);
    float4 v = *reinterpret_cast<const float4*>(
        &h[((size_t)(b * NN + m0 + row)) * F + c4 * 4]);
    Ts[row][c4 * 4 + 0] = v.x;
    Ts[row][c4 * 4 + 1] = v.y;
    Ts[row][c4 * 4 + 2] = v.z;
    Ts[row][c4 * 4 + 3] = v.w;
  }
  __syncthreads();
  for (int ci = tid; ci < 8 * F; ci += 256) {
    int nc = ci / F, f = ci % F;
    int n0 = nc * 8;
    us8 vh, vl;
#pragma unroll
    for (int j = 0; j < 8; ++j) {
      float t = Ts[n0 + j][f];
      unsigned short hi = f2bf(t);
      vh[j] = hi;
      vl[j] = f2bf(t - bf2f(hi));
    }
    int gn = m0 + n0;
    int kt = gn >> 5, kg = (gn >> 3) & 3;
    size_t off = (((size_t)b * FT + (f >> 4)) * 32 + kt) * 512 +
                 (size_t)(kg * 16 + (f & 15)) * 8;
    *reinterpret_cast<us8*>(&Oh[off]) = vh;
    *reinterpret_cast<us8*>(&Ol[off]) = vl;
  }
}

// ---------------------------------------------------------------------------
// Packed MFMA recursion step. 256 thr / 4 waves; 64 rows per block (16 per
// wave); grid 512 -> 8 waves/CU. All main-loop operands packed bf16 hi/lo,
// fragment-major: every load is one coalesced 1KB wave transaction.
// ---------------------------------------------------------------------------
template <int FT, int G>
__global__ __launch_bounds__(256) void cheb_mfma_p(
    const unsigned short* __restrict__ Lh, const unsigned short* __restrict__ Ll,
    const unsigned short* __restrict__ Bh, const unsigned short* __restrict__ Bl,
    const float* __restrict__ Tpp, float* __restrict__ Tk,
    unsigned short* __restrict__ Oh, unsigned short* __restrict__ Ol,
    const float* __restrict__ Wk, float* __restrict__ acc, float alpha,
    float beta) {
  constexpr int F = FT * 16;
  constexpr int TGN = G / 16;
  __shared__ float Ts[64][F + 1];
  __shared__ float Ws[F][G];
  const int tid = threadIdx.x;

  // same-batch -> same-XCD swizzle (HW: XCD = blockIdx % 8)
  int id = blockIdx.x;
  int xcd = id & 7, t2 = id >> 3;
  int mt = t2 & 15;
  int b = xcd + 8 * (t2 >> 4);
  const int m0 = mt * 64;

  for (int idx = tid; idx < F * G / 4; idx += 256) {
    int r = idx / (G / 4), c4 = idx % (G / 4);
    *reinterpret_cast<float4*>(&Ws[r][c4 * 4]) =
        *reinterpret_cast<const float4*>(&Wk[r * G + c4 * 4]);
  }

  const int wv = tid >> 6, l = tid & 63;
  const size_t lane8 = (size_t)l * 8;
  // wave wv owns 16-row block rb = mt*4 + wv
  const size_t Abase = (((size_t)b * 64 + mt * 4 + wv) * 32) * 512 + lane8;
  const size_t Bbase = (((size_t)b * FT) * 32) * 512 + lane8;

  f32x4 av[FT];
#pragma unroll
  for (int c = 0; c < FT; ++c) av[c] = {0.f, 0.f, 0.f, 0.f};

#pragma unroll 2
  for (int kt = 0; kt < 32; ++kt) {
    s16x8 a_h, a_l, b_h[FT], b_l[FT];
    size_t aoff = Abase + (size_t)kt * 512;
    a_h = *reinterpret_cast<const s16x8*>(&Lh[aoff]);
    a_l = *reinterpret_cast<const s16x8*>(&Ll[aoff]);
#pragma unroll
    for (int c = 0; c < FT; ++c) {
      size_t off = Bbase + ((size_t)c * 32 + kt) * 512;
      b_h[c] = *reinterpret_cast<const s16x8*>(&Bh[off]);
      b_l[c] = *reinterpret_cast<const s16x8*>(&Bl[off]);
    }
#pragma unroll
    for (int c = 0; c < FT; ++c) {
      av[c] = __builtin_amdgcn_mfma_f32_16x16x32_bf16(a_h, b_h[c], av[c], 0, 0, 0);
      av[c] = __builtin_amdgcn_mfma_f32_16x16x32_bf16(a_l, b_h[c], av[c], 0, 0, 0);
      av[c] = __builtin_amdgcn_mfma_f32_16x16x32_bf16(a_h, b_l[c], av[c], 0, 0, 0);
      av[c] = __builtin_amdgcn_mfma_f32_16x16x32_bf16(a_l, b_l[c], av[c], 0, 0, 0);
    }
  }

  // C layout: col = l&15, row = (l>>4)*4 + r  (wave wv -> rows wv*16..)
  const int kg = l >> 4, fr = l & 15;
#pragma unroll
  for (int c = 0; c < FT; ++c)
#pragma unroll
    for (int r = 0; r < 4; ++r)
      Ts[wv * 16 + kg * 4 + r][c * 16 + fr] = av[c][r];
  __syncthreads();

  // Tk = alpha*S + beta*Tpp; write fp32 Tk; update Ts
  const bool hasB = (beta != 0.f);
  for (int idx = tid; idx < 64 * (F / 4); idx += 256) {
    int row = idx / (F / 4), f0 = (idx % (F / 4)) * 4;
    size_t g = ((size_t)(b * NN + m0 + row)) * F + f0;
    float t0 = alpha * Ts[row][f0 + 0];
    float t1 = alpha * Ts[row][f0 + 1];
    float t2 = alpha * Ts[row][f0 + 2];
    float t3 = alpha * Ts[row][f0 + 3];
    if (hasB) {
      float4 p = *reinterpret_cast<const float4*>(&Tpp[g]);
      t0 = fmaf(beta, p.x, t0);
      t1 = fmaf(beta, p.y, t1);
      t2 = fmaf(beta, p.z, t2);
      t3 = fmaf(beta, p.w, t3);
    }
    float4 tv = {t0, t1, t2, t3};
    *reinterpret_cast<float4*>(&Tk[g]) = tv;
    Ts[row][f0 + 0] = t0;
    Ts[row][f0 + 1] = t1;
    Ts[row][f0 + 2] = t2;
    Ts[row][f0 + 3] = t3;
  }
  __syncthreads();

  // packed hi/lo out (next step's B operand)
  for (int ci = tid; ci < 8 * F; ci += 256) {
    int nc = ci / F, f = ci % F;
    int n0 = nc * 8;
    us8 vh, vl;
#pragma unroll
    for (int j = 0; j < 8; ++j) {
      float t = Ts[n0 + j][f];
      unsigned short hi = f2bf(t);
      vh[j] = hi;
      vl[j] = f2bf(t - bf2f(hi));
    }
    int gn = m0 + n0;
    int kt = gn >> 5, kgo = (gn >> 3) & 3;
    size_t off = (((size_t)b * FT + (f >> 4)) * 32 + kt) * 512 +
                 (size_t)(kgo * 16 + (f & 15)) * 8;
    *reinterpret_cast<us8*>(&Oh[off]) = vh;
    *reinterpret_cast<us8*>(&Ol[off]) = vl;
  }

  // fused epilogue: acc += Tk @ Wk
  const int tx = tid & 15, ty = tid >> 4;
  float o[4][TGN];
#pragma unroll
  for (int r = 0; r < 4; ++r)
#pragma unroll
    for (int c = 0; c < TGN; ++c) o[r][c] = 0.f;
#pragma unroll 8
  for (int f = 0; f < F; ++f) {
    float a[4];
#pragma unroll
    for (int r = 0; r < 4; ++r) a[r] = Ts[ty * 4 + r][f];
#pragma unroll
    for (int c = 0; c < TGN; ++c) {
      float w = Ws[f][tx * TGN + c];
#pragma unroll
      for (int r = 0; r < 4; ++r) o[r][c] = fmaf(a[r], w, o[r][c]);
    }
  }
#pragma unroll
  for (int r = 0; r < 4; ++r) {
    size_t base = ((size_t)(b * NN + m0 + ty * 4 + r)) * G + tx * TGN;
    float4 v = *reinterpret_cast<const float4*>(&acc[base]);
    v.x += o[r][0];
    v.y += o[r][1];
    v.z += o[r][2];
    v.w += o[r][3];
    *reinterpret_cast<float4*>(&acc[base]) = v;
  }
}

// ---------------------------------------------------------------------------
// Fallback fused fp32 recursion GEMM (round-2 proven path)
// ---------------------------------------------------------------------------
template <int BM, int F, int G>
__global__ __launch_bounds__(256) void cheb_gemm(
    const float* __restrict__ Lg, const float* __restrict__ Tprev,
    const float* __restrict__ Tpp, float* __restrict__ Tk,
    const float* __restrict__ Wk, float* __restrict__ acc, float alpha,
    float beta) {
  constexpr int BK = 32;
  constexpr int TM = 4, TN = 4;
  constexpr int NTX = F / TN;
  constexpr int NTY = BM / TM;
  static_assert(NTX * NTY == 256, "tile mismatch");
  constexpr int TGN = G / NTX;

  __shared__ float As[BM][BK + 1];
  __shared__ float Bs[BK][F];
  __shared__ float Ws[F][G];
  __shared__ float Ts[BM][F + 1];

  const int tid = threadIdx.x;
  const int tx = tid % NTX, ty = tid / NTX;
  const int b = blockIdx.y;
  const int i0 = blockIdx.x * BM;

  constexpr int W_ITERS = (F * G / 4) / 256;
#pragma unroll
  for (int it = 0; it < W_ITERS; ++it) {
    int idx = tid + it * 256;
    int r = idx / (G / 4), c4 = idx % (G / 4);
    float4 v = *reinterpret_cast<const float4*>(&Wk[r * G + c4 * 4]);
    *reinterpret_cast<float4*>(&Ws[r][c4 * 4]) = v;
  }

  float accT[TM][TN];
#pragma unroll
  for (int r = 0; r < TM; ++r)
#pragma unroll
    for (int c = 0; c < TN; ++c) accT[r][c] = 0.f;

  const size_t Lbase = ((size_t)b << 20);
  constexpr int A_ITERS = (BM * (BK / 4)) / 256;
  constexpr int B_ITERS = (BK * (F / 4) + 255) / 256;

  for (int k0 = 0; k0 < NN; k0 += BK) {
#pragma unroll
    for (int it = 0; it < A_ITERS; ++it) {
      int idx = tid + it * 256;
      int m = idx >> 3, k4 = idx & 7;
      float4 v = *reinterpret_cast<const float4*>(
          &Lg[Lbase + (size_t)(i0 + m) * NN + k0 + k4 * 4]);
      As[m][k4 * 4 + 0] = v.x;
      As[m][k4 * 4 + 1] = v.y;
      As[m][k4 * 4 + 2] = v.z;
      As[m][k4 * 4 + 3] = v.w;
    }
#pragma unroll
    for (int it = 0; it < B_ITERS; ++it) {
      int idx = tid + it * 256;
      int kr = idx / (F / 4), c4 = idx % (F / 4);
      float4 v = *reinterpret_cast<const float4*>(
          &Tprev[(size_t)(b * NN + k0 + kr) * F + c4 * 4]);
      *reinterpret_cast<float4*>(&Bs[kr][c4 * 4]) = v;
    }
    __syncthreads();
#pragma unroll
    for (int kk = 0; kk < BK; ++kk) {
      float a[TM];
#pragma unroll
      for (int r = 0; r < TM; ++r) a[r] = As[ty * TM + r][kk];
      float4 bv = *reinterpret_cast<const float4*>(&Bs[kk][tx * TN]);
      float bb[4] = {bv.x, bv.y, bv.z, bv.w};
#pragma unroll
      for (int r = 0; r < TM; ++r)
#pragma unroll
        for (int c = 0; c < TN; ++c)
          accT[r][c] = fmaf(a[r], bb[c], accT[r][c]);
    }
    __syncthreads();
  }

  const bool hasB = (beta != 0.f);
#pragma unroll
  for (int r = 0; r < TM; ++r) {
    int row = i0 + ty * TM + r;
    size_t gidx = (size_t)(b * NN + row) * F + tx * TN;
    float t0 = alpha * accT[r][0], t1 = alpha * accT[r][1];
    float t2 = alpha * accT[r][2], t3 = alpha * accT[r][3];
    if (hasB) {
      float4 p = *reinterpret_cast<const float4*>(&Tpp[gidx]);
      t0 = fmaf(beta, p.x, t0);
      t1 = fmaf(beta, p.y, t1);
      t2 = fmaf(beta, p.z, t2);
      t3 = fmaf(beta, p.w, t3);
    }
    float4 tv = {t0, t1, t2, t3};
    *reinterpret_cast<float4*>(&Tk[gidx]) = tv;
    Ts[ty * TM + r][tx * TN + 0] = t0;
    Ts[ty * TM + r][tx * TN + 1] = t1;
    Ts[ty * TM + r][tx * TN + 2] = t2;
    Ts[ty * TM + r][tx * TN + 3] = t3;
  }
  __syncthreads();

  float oacc[TM][TGN];
#pragma unroll
  for (int r = 0; r < TM; ++r)
#pragma unroll
    for (int c = 0; c < TGN; ++c) oacc[r][c] = 0.f;
#pragma unroll 8
  for (int f = 0; f < F; ++f) {
    float a[TM];
#pragma unroll
    for (int r = 0; r < TM; ++r) a[r] = Ts[ty * TM + r][f];
#pragma unroll
    for (int c = 0; c < TGN; ++c) {
      float w = Ws[f][tx * TGN + c];
#pragma unroll
      for (int r = 0; r < TM; ++r) oacc[r][c] = fmaf(a[r], w, oacc[r][c]);
    }
  }
#pragma unroll
  for (int r = 0; r < TM; ++r) {
    int row = i0 + ty * TM + r;
    size_t base = (size_t)(b * NN + row) * G + tx * TGN;
#pragma unroll
    for (int c = 0; c < TGN; ++c) acc[base + c] += oacc[r][c];
  }
}

// ---------------------------------------------------------------------------
// BatchNorm (train, biased var) + ELU
// ---------------------------------------------------------------------------
constexpr int BN_BLOCKS = 256;

template <int C>
__global__ __launch_bounds__(256) void bn_part(const float* __restrict__ acc,
                                               double* __restrict__ part) {
  constexpr int GR = 256 / C;
  const int tid = threadIdx.x;
  const int c = tid % C;
  const int g = tid / C;
  double s = 0.0, s2 = 0.0;
  for (int r = blockIdx.x * GR + g; r < ROWS; r += BN_BLOCKS * GR) {
    double v = (double)acc[(size_t)r * C + c];
    s += v;
    s2 += v * v;
  }
  __shared__ double Ls[256], Ls2[256];
  Ls[tid] = s;
  Ls2[tid] = s2;
  __syncthreads();
  for (int str = 128; str >= C; str >>= 1) {
    if (tid < str) {
      Ls[tid] += Ls[tid + str];
      Ls2[tid] += Ls2[tid + str];
    }
    __syncthreads();
  }
  if (tid < C) {
    part[(size_t)blockIdx.x * 2 * C + tid] = Ls[tid];
    part[(size_t)blockIdx.x * 2 * C + C + tid] = Ls2[tid];
  }
}

template <int C>
__global__ void bn_final(const double* __restrict__ part,
                         const float* __restrict__ g,
                         const float* __restrict__ be,
                         float* __restrict__ sc) {
  int t = threadIdx.x;
  if (t < C) {
    double s = 0.0, s2 = 0.0;
    for (int b = 0; b < BN_BLOCKS; ++b) {
      s += part[(size_t)b * 2 * C + t];
      s2 += part[(size_t)b * 2 * C + C + t];
    }
    double mu = s / ROWS;
    double var = s2 / ROWS - mu * mu;
    float scale = g[t] / sqrtf((float)var + 1e-5f);
    sc[t] = scale;
    sc[C + t] = be[t] - (float)mu * scale;
  }
}

template <int C>
__global__ __launch_bounds__(256) void bn_apply_elu(
    const float* __restrict__ acc, const float* __restrict__ sc,
    float* __restrict__ h) {
  const long total4 = (long)ROWS * C / 4;
  for (long idx = (long)blockIdx.x * 256 + threadIdx.x; idx < total4;
       idx += (long)gridDim.x * 256) {
    long base = idx * 4;
    int c0 = (int)(base % C);
    float4 v = reinterpret_cast<const float4*>(acc)[idx];
    float t0 = fmaf(v.x, sc[c0 + 0], sc[C + c0 + 0]);
    float t1 = fmaf(v.y, sc[c0 + 1], sc[C + c0 + 1]);
    float t2 = fmaf(v.z, sc[c0 + 2], sc[C + c0 + 2]);
    float t3 = fmaf(v.w, sc[c0 + 3], sc[C + c0 + 3]);
    float4 o;
    o.x = t0 > 0.f ? t0 : expm1f(t0);
    o.y = t1 > 0.f ? t1 : expm1f(t1);
    o.z = t2 > 0.f ? t2 : expm1f(t2);
    o.w = t3 > 0.f ? t3 : expm1f(t3);
    reinterpret_cast<float4*>(h)[idx] = o;
  }
}

// ---------------------------------------------------------------------------
__global__ __launch_bounds__(256) void final_k(const float* __restrict__ h,
                                               const float* __restrict__ Wfc,
                                               const float* __restrict__ bfc,
                                               float* __restrict__ out) {
  const int b = blockIdx.x;
  const int tid = threadIdx.x;
  const int c = tid % 64;
  const int g = tid / 64;
  float s = 0.f;
  for (int r = g; r < NN; r += 4) s += h[(size_t)(b * NN + r) * 64 + c];
  __shared__ float red[256];
  red[tid] = s;
  __syncthreads();
  if (tid < 128) red[tid] += red[tid + 128];
  __syncthreads();
  if (tid < 64) {
    float pooled = (red[tid] + red[tid + 64]) * (1.0f / 1024.0f);
    float v = pooled * Wfc[tid];
#pragma unroll
    for (int off = 32; off; off >>= 1) v += __shfl_down(v, off, 64);
    if (tid == 0) out[b] = v + bfc[0];
  }
}

// ---------------------------------------------------------------------------
extern "C" void kernel_launch(void* const* d_in, const int* in_sizes, int n_in,
                              void* d_out, int out_size, void* d_ws,
                              size_t ws_size, hipStream_t stream) {
  const float* x = (const float*)d_in[0];
  float* A = (float*)d_in[1];  // overwritten in place (W then fp32 L)
  const float* W1 = (const float*)d_in[2];
  const float* g1 = (const float*)d_in[4];
  const float* be1 = (const float*)d_in[5];
  const float* W2 = (const float*)d_in[6];
  const float* g2 = (const float*)d_in[8];
  const float* be2 = (const float*)d_in[9];
  const float* W3 = (const float*)d_in[10];
  const float* g3 = (const float*)d_in[12];
  const float* be3 = (const float*)d_in[13];
  const float* Wfc = (const float*)d_in[14];
  const float* bfc = (const float*)d_in[15];

  constexpr size_t TBUF = 2097152;   // 32768*64 floats (8MB)
  float* wsf = (float*)d_ws;
  float* buf0 = wsf;
  float* buf1 = buf0 + TBUF;
  float* buf2 = buf1 + TBUF;
  float* acc = buf2 + TBUF;
  // packed T slots: 4 arrays x 2,097,152 ushorts (4MB each)
  unsigned short* tt = (unsigned short*)(wsf + 4 * TBUF);
  unsigned short* TTh[2] = {tt, tt + 2 * 2097152};
  unsigned short* TTl[2] = {tt + 2097152, tt + 3 * 2097152};
  // packed L hi/lo: 33,554,432 ushorts each (64MB)
  unsigned short* Lh = (unsigned short*)(wsf + 4 * TBUF + 4194304);
  unsigned short* Ll = Lh + (size_t)NB * NN * NN;
  float* S = wsf + 4 * TBUF + 4194304 + 2 * ((size_t)NB * NN * NN / 2);
  float* D = S + (size_t)NSLICE * ROWS;
  double* part_m = (double*)(D + ROWS);
  float* sc_m = (float*)(part_m + (size_t)BN_BLOCKS * 2 * 64);
  size_t need_m = (size_t)((sc_m + 128) - wsf) * sizeof(float);

  // fallback layout (no packed regions)
  float* S_f = wsf + 4 * TBUF;
  float* D_f = S_f + (size_t)NSLICE * ROWS;
  double* part_f = (double*)(D_f + ROWS);
  float* sc_f = (float*)(part_f + (size_t)BN_BLOCKS * 2 * 64);
  size_t need_f = (size_t)((sc_f + 128) - wsf) * sizeof(float);

  const bool use_m = (ws_size >= need_m);
  if (!use_m && ws_size < need_f) return;
  float* Sp = use_m ? S : S_f;
  float* Dp = use_m ? D : D_f;
  double* part = use_m ? part_m : part_f;
  float* sc = use_m ? sc_m : sc_f;

  float* bufs[3] = {buf0, buf1, buf2};

  // ---- Laplacian ----
  colsum_w<<<dim3(4, NSLICE, NB), 256, 0, stream>>>(A, x, Sp);
  d_kernel<<<128, 256, 0, stream>>>(Sp, Dp);
  if (use_m) {
    pack_L<<<dim3(64, NB), 256, 0, stream>>>(A, Dp, Lh, Ll);
  } else {
    scale_L<<<4096, 256, 0, stream>>>(A, Dp);
  }

  // ---- layer 1: F=3 -> G=32, fp32 path (L fp32 in A) ----
  acc0_gemm<3, 32><<<512, 256, 0, stream>>>(x, W1, acc);
  {
    const float* Tm1 = x;
    const float* Tm2 = nullptr;
    for (int k = 1; k <= 8; ++k) {
      float* outb = bufs[k % 3];
      float alpha = (k == 1) ? 1.f : 2.f;
      float beta = (k == 1) ? 0.f : -1.f;
      cheb_l1<<<dim3(64, NB), 256, 0, stream>>>(
          A, Tm1, (k == 1) ? x : Tm2, outb, W1 + k * 3 * 32, acc, alpha, beta);
      Tm2 = Tm1;
      Tm1 = outb;
    }
  }
  bn_part<32><<<BN_BLOCKS, 256, 0, stream>>>(acc, part);
  bn_final<32><<<1, 64, 0, stream>>>(part, g1, be1, sc);
  bn_apply_elu<32><<<1024, 256, 0, stream>>>(acc, sc, buf0);  // h1 -> buf0

  // ---- layer 2: F=32 -> G=64 ----
  acc0_gemm<32, 64><<<512, 256, 0, stream>>>(buf0, W2, acc);
  if (use_m) {
    pack_T<2><<<dim3(16, NB), 256, 0, stream>>>(buf0, TTh[0], TTl[0]);
    const float* Tm1 = buf0;
    const float* Tm2 = nullptr;
    for (int k = 1; k <= 8; ++k) {
      float* outb = bufs[k % 3];
      int si = (k - 1) & 1, so = k & 1;
      float alpha = (k == 1) ? 1.f : 2.f;
      float beta = (k == 1) ? 0.f : -1.f;
      cheb_mfma_p<2, 64><<<512, 256, 0, stream>>>(
          Lh, Ll, TTh[si], TTl[si], (k == 1) ? buf0 : Tm2, outb, TTh[so],
          TTl[so], W2 + k * 32 * 64, acc, alpha, beta);
      Tm2 = Tm1;
      Tm1 = outb;
    }
  } else {
    const float* Tm1 = buf0;
    const float* Tm2 = nullptr;
    for (int k = 1; k <= 8; ++k) {
      float* outb = bufs[k % 3];
      float alpha = (k == 1) ? 1.f : 2.f;
      float beta = (k == 1) ? 0.f : -1.f;
      cheb_gemm<128, 32, 64><<<dim3(8, NB), 256, 0, stream>>>(
          A, Tm1, (k == 1) ? buf0 : Tm2, outb, W2 + k * 32 * 64, acc, alpha,
          beta);
      Tm2 = Tm1;
      Tm1 = outb;
    }
  }
  bn_part<64><<<BN_BLOCKS, 256, 0, stream>>>(acc, part);
  bn_final<64><<<1, 64, 0, stream>>>(part, g2, be2, sc);
  bn_apply_elu<64><<<2048, 256, 0, stream>>>(acc, sc, buf0);  // h2 -> buf0

  // ---- layer 3: F=64 -> G=64 ----
  acc0_gemm<64, 64><<<512, 256, 0, stream>>>(buf0, W3, acc);
  if (use_m) {
    pack_T<4><<<dim3(16, NB), 256, 0, stream>>>(buf0, TTh[0], TTl[0]);
    const float* Tm1 = buf0;
    const float* Tm2 = nullptr;
    for (int k = 1; k <= 8; ++k) {
      float* outb = bufs[k % 3];
      int si = (k - 1) & 1, so = k & 1;
      float alpha = (k == 1) ? 1.f : 2.f;
      float beta = (k == 1) ? 0.f : -1.f;
      cheb_mfma_p<4, 64><<<512, 256, 0, stream>>>(
          Lh, Ll, TTh[si], TTl[si], (k == 1) ? buf0 : Tm2, outb, TTh[so],
          TTl[so], W3 + k * 64 * 64, acc, alpha, beta);
      Tm2 = Tm1;
      Tm1 = outb;
    }
  } else {
    const float* Tm1 = buf0;
    const float* Tm2 = nullptr;
    for (int k = 1; k <= 8; ++k) {
      float* outb = bufs[k % 3];
      float alpha = (k == 1) ? 1.f : 2.f;
      float beta = (k == 1) ? 0.f : -1.f;
      cheb_gemm<64, 64, 64><<<dim3(16, NB), 256, 0, stream>>>(
          A, Tm1, (k == 1) ? buf0 : Tm2, outb, W3 + k * 64 * 64, acc, alpha,
          beta);
      Tm2 = Tm1;
      Tm1 = outb;
    }
  }
  bn_part<64><<<BN_BLOCKS, 256, 0, stream>>>(acc, part);
  bn_final<64><<<1, 64, 0, stream>>>(part, g3, be3, sc);
  bn_apply_elu<64><<<2048, 256, 0, stream>>>(acc, sc, buf0);  // h3 -> buf0

  // ---- head ----
  final_k<<<NB, 256, 0, stream>>>(buf0, Wfc, bfc, (float*)d_out);
}